// Round 1
// baseline (1227.611 us; speedup 1.0000x reference)
//
#include <hip/hip_runtime.h>

#define N_NODES 50000
#define N_EDGES 800000
#define NFEAT   128
#define NHID    256
#define NCLASS  64

// ---- binning geometry ----
// R14 theory: prep_fill's 45us == 800k device-scope atomicAdd at ~1/cyc/XCD.
// Replace per-edge position atomics with 56-bucket binning (11k global atomics)
// + LDS f32 accumulation (ds_add_f32 is bank-parallel, not L2-serialized).
#define NBUCK   56
#define BWIDTH  896                      // 7*128: fine 128-node ranges never straddle buckets
#define BCAP    16384                    // mean 14336, +17 sigma headroom
#define BIN_CH  4096                     // edges per bin block
#define BIN_B   ((N_EDGES + BIN_CH - 1) / BIN_CH)   // 196
#define NFINE   ((N_NODES + 127) / 128)  // 391 fine dst ranges
#define FPB     7                        // fine ranges per bucket
#define QCAP    4096                     // hit queue per acc block (mean 2048, +45 sigma)

#define CVTX_B  ((N_NODES * 32 + 255) / 256)      // 6250
#define CVTW_B  (((65536 + 32768) + 255) / 256)   // 384

typedef unsigned short u16;
typedef unsigned int   u32;
typedef __attribute__((ext_vector_type(8))) short s16x8;
typedef __attribute__((ext_vector_type(4))) float f32x4;

__device__ inline u16 f2bf(float f) {
    u32 u = __float_as_uint(f);
    u32 r = (u + 0x7FFFu + ((u >> 16) & 1u)) >> 16;   // RNE
    return (u16)r;
}
__device__ inline float bflo(u32 v) { return __uint_as_float(v << 16); }
__device__ inline float bfhi(u32 v) { return __uint_as_float(v & 0xFFFF0000u); }

// async global->LDS, 16B per lane; LDS dest must be wave-uniform base + lane*16
#define GLOAD_LDS16(g, l)                                                        \
    __builtin_amdgcn_global_load_lds(                                            \
        (const __attribute__((address_space(1))) u32*)(const void*)(g),          \
        (__attribute__((address_space(3))) u32*)(void*)(l), 16, 0, 0)

// ---------------- fused prep: edge binning | cvt_x | cvt_w ----------------
// Bin block: LDS histogram ranks (cheap) + 56 global reservation atomics.
// Output: bbuf[bucket][pos] = (dst<<16)|src, contiguous per bucket.
__global__ __launch_bounds__(256) void prep_kernel(const float* __restrict__ x,
                                                   const int* __restrict__ ei,
                                                   const float* __restrict__ W1r,
                                                   const float* __restrict__ W1n,
                                                   const float* __restrict__ W2n,
                                                   const float* __restrict__ W2r,
                                                   u16* __restrict__ xa,
                                                   u32* __restrict__ gcnt,
                                                   u32* __restrict__ bbuf,
                                                   u16* __restrict__ W1t,
                                                   u16* __restrict__ W2t) {
    int b = blockIdx.x;
    if (b < BIN_B) {
        __shared__ u32 hist[NBUCK];
        __shared__ u32 base[NBUCK];
        int tid = threadIdx.x;
        if (tid < NBUCK) hist[tid] = 0;
        __syncthreads();
        u32 ek[16]; u32 rk[16]; int bk[16];
        int i0 = b * BIN_CH;
        #pragma unroll
        for (int k = 0; k < 16; ++k) {
            int i = i0 + k * 256 + tid;
            bk[k] = -1;
            if (i < N_EDGES) {
                u32 s = (u32)ei[i];
                u32 d = (u32)ei[N_EDGES + i];
                int bu = (int)(d / BWIDTH);
                ek[k] = (d << 16) | s;
                bk[k] = bu;
                rk[k] = atomicAdd(&hist[bu], 1u);   // LDS rank
            }
        }
        __syncthreads();
        if (tid < NBUCK) base[tid] = atomicAdd(&gcnt[tid], hist[tid]);  // 56 global atomics/block
        __syncthreads();
        #pragma unroll
        for (int k = 0; k < 16; ++k) {
            if (bk[k] >= 0) {
                u32 pos = base[bk[k]] + rk[k];
                if (pos < BCAP) bbuf[((u32)bk[k] << 14) + pos] = ek[k];
            }
        }
    } else if (b < BIN_B + CVTX_B) {
        int idx = (b - BIN_B) * 256 + threadIdx.x;
        if (idx >= N_NODES * 32) return;
        int r  = idx >> 5;
        int c4 = (idx & 31) * 4;
        float4 v = *reinterpret_cast<const float4*>(x + (size_t)r * NFEAT + c4);
        uint2 o;
        o.x = (u32)f2bf(v.x) | ((u32)f2bf(v.y) << 16);
        o.y = (u32)f2bf(v.z) | ((u32)f2bf(v.w) << 16);
        *reinterpret_cast<uint2*>(xa + (size_t)r * 256 + c4) = o;   // cols 0..127 of combined row
    } else {
        int id = (b - BIN_B - CVTX_B) * 256 + threadIdx.x;
        if (id < 65536) {
            int k = id & 255, n = id >> 8;
            float v = (k < NFEAT) ? W1r[(size_t)k * NHID + n]
                                  : W1n[(size_t)(k - NFEAT) * NHID + n];
            W1t[(size_t)n * 256 + k] = f2bf(v);
        } else if (id < 65536 + 32768) {
            int j = id - 65536;
            int k = j & 255, n = j >> 8;
            float v = (n < NCLASS) ? W2n[(size_t)k * NCLASS + n]
                                   : W2r[(size_t)k * NCLASS + (n - NCLASS)];
            W2t[(size_t)n * 256 + k] = f2bf(v);
        }
    }
}

// ---------------- acc1: xa[n][128:256] = mean of xa[s][0:128] ----------------
// One block per (fine 128-node range, feature half). Grid XCD-swizzled so a
// bucket's 14 blocks share one XCD's L2 copy of the bucket. Phase A compacts
// hits into an LDS queue; phase B: 2 edges/wave, 16-pair MLP batches, ds_add_f32.
__global__ __launch_bounds__(256) void acc1_kernel(const u32* __restrict__ bbuf,
                                                   const u32* __restrict__ gcnt,
                                                   u16* __restrict__ xa) {
    __shared__ float acc[128][65];   // +1 pad decorrelates banks across dl
    __shared__ u32   q[QCAP];
    __shared__ int   scnt[128];
    __shared__ float sinv[128];
    __shared__ u32   qn;

    int tid = threadIdx.x, lane = tid & 63, wid = tid >> 6;
    int x8 = blockIdx.x & 7, qb = blockIdx.x >> 3;     // qb 0..97
    int cb = x8 + 8 * (qb / 14);                       // bucket, matches XCD
    int r14 = qb % 14;
    int f = cb * FPB + (r14 >> 1);
    int half = r14 & 1;
    if (f >= NFINE) return;
    int n0 = f * 128;

    for (int i = tid; i < 128 * 65; i += 256) (&acc[0][0])[i] = 0.0f;
    if (tid < 128) scnt[tid] = 0;
    if (tid == 0) qn = 0;
    __syncthreads();

    // phase A: scan bucket, compact hits (hit rate ~2%/7)
    int m = (int)gcnt[cb]; if (m > BCAP) m = BCAP;
    const u32* bk = bbuf + ((u32)cb << 14);
    int i = tid;
    for (; i + 768 < m; i += 1024) {
        u32 e0 = bk[i], e1 = bk[i + 256], e2 = bk[i + 512], e3 = bk[i + 768];
        if ((u32)((e0 >> 16) - n0) < 128u) { u32 r = atomicAdd(&qn, 1u); if (r < QCAP) q[r] = e0; }
        if ((u32)((e1 >> 16) - n0) < 128u) { u32 r = atomicAdd(&qn, 1u); if (r < QCAP) q[r] = e1; }
        if ((u32)((e2 >> 16) - n0) < 128u) { u32 r = atomicAdd(&qn, 1u); if (r < QCAP) q[r] = e2; }
        if ((u32)((e3 >> 16) - n0) < 128u) { u32 r = atomicAdd(&qn, 1u); if (r < QCAP) q[r] = e3; }
    }
    for (; i < m; i += 256) {
        u32 e = bk[i];
        if ((u32)((e >> 16) - n0) < 128u) { u32 r = atomicAdd(&qn, 1u); if (r < QCAP) q[r] = e; }
    }
    __syncthreads();
    int nq = (int)qn; if (nq > QCAP) nq = QCAP;

    // phase B: lanes 0-31 = edge A, lanes 32-63 = edge B; 16 pairs in flight
    const u32* xu = reinterpret_cast<const u32*>(xa);   // row stride 128 u32
    int l31 = lane & 31, sel = lane >> 5;
    int soff = half * 32 + l31;                          // u32 col in source row
    for (int rb = wid * 32; rb < nq; rb += 128) {
        u32 w[16]; int dl[16]; bool v[16];
        #pragma unroll
        for (int p = 0; p < 16; ++p) {
            int j = rb + 2 * p + sel;
            v[p] = (j < nq);
            u32 e = v[p] ? q[j] : 0u;
            dl[p] = (int)(e >> 16) - n0;
            w[p] = v[p] ? xu[(size_t)(e & 0xFFFFu) * 128 + soff] : 0u;
        }
        #pragma unroll
        for (int p = 0; p < 16; ++p) {
            if (v[p]) {
                atomicAdd(&acc[dl[p]][2 * l31],     bflo(w[p]));
                atomicAdd(&acc[dl[p]][2 * l31 + 1], bfhi(w[p]));
                if (l31 == 0) atomicAdd(&scnt[dl[p]], 1);
            }
        }
    }
    __syncthreads();
    if (tid < 128) sinv[tid] = 1.0f / fmaxf((float)scnt[tid], 1.0f);
    __syncthreads();

    // epilogue: write bf16 means, this half's 64 features -> u32 cols 64+half*32 ..
    for (int k = tid; k < 128 * 32; k += 256) {
        int r = k >> 5, cu = k & 31;
        int node = n0 + r;
        if (node < N_NODES) {
            float iv = sinv[r];
            u32 pk = (u32)f2bf(acc[r][2 * cu] * iv) | ((u32)f2bf(acc[r][2 * cu + 1] * iv) << 16);
            reinterpret_cast<u32*>(xa)[(size_t)node * 128 + 64 + half * 32 + cu] = pk;
        }
    }
}

// ---------------- acc2: out[n][:] += mean of t[s][:] (t bf16 64-wide) ----------------
__global__ __launch_bounds__(256) void acc2_kernel(const u32* __restrict__ bbuf,
                                                   const u32* __restrict__ gcnt,
                                                   const u16* __restrict__ t,
                                                   float* __restrict__ out) {
    __shared__ float acc[128][65];
    __shared__ u32   q[QCAP];
    __shared__ int   scnt[128];
    __shared__ float sinv[128];
    __shared__ u32   qn;

    int tid = threadIdx.x, lane = tid & 63, wid = tid >> 6;
    int x8 = blockIdx.x & 7, qb = blockIdx.x >> 3;     // qb 0..48
    int cb = x8 + 8 * (qb / 7);
    int f = cb * FPB + qb % 7;
    if (f >= NFINE) return;
    int n0 = f * 128;

    for (int i = tid; i < 128 * 65; i += 256) (&acc[0][0])[i] = 0.0f;
    if (tid < 128) scnt[tid] = 0;
    if (tid == 0) qn = 0;
    __syncthreads();

    int m = (int)gcnt[cb]; if (m > BCAP) m = BCAP;
    const u32* bk = bbuf + ((u32)cb << 14);
    int i = tid;
    for (; i + 768 < m; i += 1024) {
        u32 e0 = bk[i], e1 = bk[i + 256], e2 = bk[i + 512], e3 = bk[i + 768];
        if ((u32)((e0 >> 16) - n0) < 128u) { u32 r = atomicAdd(&qn, 1u); if (r < QCAP) q[r] = e0; }
        if ((u32)((e1 >> 16) - n0) < 128u) { u32 r = atomicAdd(&qn, 1u); if (r < QCAP) q[r] = e1; }
        if ((u32)((e2 >> 16) - n0) < 128u) { u32 r = atomicAdd(&qn, 1u); if (r < QCAP) q[r] = e2; }
        if ((u32)((e3 >> 16) - n0) < 128u) { u32 r = atomicAdd(&qn, 1u); if (r < QCAP) q[r] = e3; }
    }
    for (; i < m; i += 256) {
        u32 e = bk[i];
        if ((u32)((e >> 16) - n0) < 128u) { u32 r = atomicAdd(&qn, 1u); if (r < QCAP) q[r] = e; }
    }
    __syncthreads();
    int nq = (int)qn; if (nq > QCAP) nq = QCAP;

    const u32* tu = reinterpret_cast<const u32*>(t);    // row stride 32 u32
    int l31 = lane & 31, sel = lane >> 5;
    for (int rb = wid * 32; rb < nq; rb += 128) {
        u32 w[16]; int dl[16]; bool v[16];
        #pragma unroll
        for (int p = 0; p < 16; ++p) {
            int j = rb + 2 * p + sel;
            v[p] = (j < nq);
            u32 e = v[p] ? q[j] : 0u;
            dl[p] = (int)(e >> 16) - n0;
            w[p] = v[p] ? tu[(size_t)(e & 0xFFFFu) * 32 + l31] : 0u;
        }
        #pragma unroll
        for (int p = 0; p < 16; ++p) {
            if (v[p]) {
                atomicAdd(&acc[dl[p]][2 * l31],     bflo(w[p]));
                atomicAdd(&acc[dl[p]][2 * l31 + 1], bfhi(w[p]));
                if (l31 == 0) atomicAdd(&scnt[dl[p]], 1);
            }
        }
    }
    __syncthreads();
    if (tid < 128) sinv[tid] = 1.0f / fmaxf((float)scnt[tid], 1.0f);
    __syncthreads();

    for (int k = tid; k < 128 * 32; k += 256) {
        int r = k >> 5, c2 = k & 31;
        int node = n0 + r;
        if (node < N_NODES) {
            float iv = sinv[r];
            float2* op = reinterpret_cast<float2*>(out + (size_t)node * NCLASS) + c2;
            float2 vv = *op;
            vv.x += acc[r][2 * c2] * iv;
            vv.y += acc[r][2 * c2 + 1] * iv;
            *op = vv;
        }
    }
}

// ---------------- MFMA GEMM 1: h = relu(xa @ W1t^T + b1), bf16 out ----------------
// R12-proven shape: BM=128, BN=128 (dim3 grid), LDS 16 KB, acc[4][4].
__global__ __launch_bounds__(256) void gemm1_mfma(const u16* __restrict__ xa,
                                                  const u16* __restrict__ W1t,
                                                  const float* __restrict__ b1,
                                                  u16* __restrict__ h) {
    __shared__ u16 As[128 * 32];
    __shared__ u16 Bs[128 * 32];
    const int tid = threadIdx.x;
    const int r0 = blockIdx.x * 128;
    const int n0 = blockIdx.y * 128;
    const int wid = tid >> 6, ln = tid & 63;
    const int wm = (wid & 1) * 64, wn = (wid >> 1) * 64;
    const int lr = ln & 15;
    const int lq = ln >> 4;

    f32x4 acc[4][4] = {};

    for (int k0 = 0; k0 < 256; k0 += 32) {
        #pragma unroll
        for (int it = 0; it < 2; ++it) {
            int c   = it * 256 + tid;
            int row = c >> 2;
            int ko  = (c & 3) * 8;
            GLOAD_LDS16(xa  + (size_t)(r0 + row) * 256 + k0 + ko, As + c * 8);
            GLOAD_LDS16(W1t + (size_t)(n0 + row) * 256 + k0 + ko, Bs + c * 8);
        }
        __syncthreads();

        s16x8 af[4], bf[4];
        #pragma unroll
        for (int i = 0; i < 4; ++i)
            af[i] = *reinterpret_cast<const s16x8*>(As + (wm + i * 16 + lr) * 32 + lq * 8);
        #pragma unroll
        for (int j = 0; j < 4; ++j)
            bf[j] = *reinterpret_cast<const s16x8*>(Bs + (wn + j * 16 + lr) * 32 + lq * 8);
        #pragma unroll
        for (int i = 0; i < 4; ++i)
            #pragma unroll
            for (int j = 0; j < 4; ++j)
                acc[i][j] = __builtin_amdgcn_mfma_f32_16x16x32_bf16(af[i], bf[j], acc[i][j], 0, 0, 0);
        __syncthreads();
    }

    #pragma unroll
    for (int i = 0; i < 4; ++i) {
        #pragma unroll
        for (int j = 0; j < 4; ++j) {
            int col = n0 + wn + j * 16 + lr;
            float bias = b1[col];
            #pragma unroll
            for (int r = 0; r < 4; ++r) {
                int row = r0 + wm + i * 16 + lq * 4 + r;
                if (row < N_NODES)
                    h[(size_t)row * 256 + col] = f2bf(fmaxf(acc[i][j][r] + bias, 0.0f));
            }
        }
    }
}

// ---------------- MFMA GEMM 2 (fused): cols 0..63 -> t (bf16), 64..127 -> out+b2 (f32) ----------------
__global__ __launch_bounds__(256) void gemm2_mfma(const u16* __restrict__ h,
                                                  const u16* __restrict__ W2t,
                                                  const float* __restrict__ b2,
                                                  u16* __restrict__ t,
                                                  float* __restrict__ out) {
    __shared__ u16 As[128 * 32];
    __shared__ u16 Bs[128 * 32];
    const int tid = threadIdx.x;
    const int r0 = blockIdx.x * 128;
    const int wid = tid >> 6, ln = tid & 63;
    const int wm = (wid & 1) * 64, wn = (wid >> 1) * 64;
    const int lr = ln & 15;
    const int lq = ln >> 4;

    f32x4 acc[4][4] = {};

    for (int k0 = 0; k0 < 256; k0 += 32) {
        #pragma unroll
        for (int it = 0; it < 2; ++it) {
            int c   = it * 256 + tid;
            int row = c >> 2;
            int ko  = (c & 3) * 8;
            GLOAD_LDS16(h   + (size_t)(r0 + row) * 256 + k0 + ko, As + c * 8);
            GLOAD_LDS16(W2t + (size_t)row * 256 + k0 + ko,        Bs + c * 8);
        }
        __syncthreads();

        s16x8 af[4], bf[4];
        #pragma unroll
        for (int i = 0; i < 4; ++i)
            af[i] = *reinterpret_cast<const s16x8*>(As + (wm + i * 16 + lr) * 32 + lq * 8);
        #pragma unroll
        for (int j = 0; j < 4; ++j)
            bf[j] = *reinterpret_cast<const s16x8*>(Bs + (wn + j * 16 + lr) * 32 + lq * 8);
        #pragma unroll
        for (int i = 0; i < 4; ++i)
            #pragma unroll
            for (int j = 0; j < 4; ++j)
                acc[i][j] = __builtin_amdgcn_mfma_f32_16x16x32_bf16(af[i], bf[j], acc[i][j], 0, 0, 0);
        __syncthreads();
    }

    #pragma unroll
    for (int i = 0; i < 4; ++i) {
        #pragma unroll
        for (int j = 0; j < 4; ++j) {
            int col = wn + j * 16 + lr;   // 0..127
            #pragma unroll
            for (int r = 0; r < 4; ++r) {
                int row = r0 + wm + i * 16 + lq * 4 + r;
                if (row >= N_NODES) continue;
                if (col < NCLASS) {
                    t[(size_t)row * NCLASS + col] = f2bf(acc[i][j][r]);
                } else {
                    int c = col - NCLASS;
                    out[(size_t)row * NCLASS + c] = acc[i][j][r] + b2[c];
                }
            }
        }
    }
}

extern "C" void kernel_launch(void* const* d_in, const int* in_sizes, int n_in,
                              void* d_out, int out_size, void* d_ws, size_t ws_size,
                              hipStream_t stream) {
    const float* x    = (const float*)d_in[0];
    const int*   ei   = (const int*)d_in[1];
    const float* W1n  = (const float*)d_in[2];
    const float* W1r  = (const float*)d_in[3];
    const float* b1   = (const float*)d_in[4];
    const float* W2n  = (const float*)d_in[5];
    const float* W2r  = (const float*)d_in[6];
    const float* b2   = (const float*)d_in[7];
    float* out = (float*)d_out;

    // workspace: gcnt u32[64] | bbuf u32[56<<14] | xa u16[50000*256] | h u16[50000*256]
    //          | t u16[50000*64] | W1t u16[65536] | W2t u16[32768]
    u32* gcnt = (u32*)d_ws;
    u32* bbuf = gcnt + 64;
    u16* xa   = (u16*)(bbuf + ((size_t)NBUCK << 14));
    u16* h    = xa + (size_t)N_NODES * 256;
    u16* t    = h  + (size_t)N_NODES * 256;
    u16* W1t  = t  + (size_t)N_NODES * 64;
    u16* W2t  = W1t + 65536;

    hipMemsetAsync(gcnt, 0, 64 * sizeof(u32), stream);

    // bin edges + bf16 converts (one dispatch)
    prep_kernel<<<BIN_B + CVTX_B + CVTW_B, 256, 0, stream>>>(
        x, ei, W1r, W1n, W2n, W2r, xa, gcnt, bbuf, W1t, W2t);

    // layer 1: LDS-accumulate mean, then GEMM
    acc1_kernel<<<8 * 98, 256, 0, stream>>>(bbuf, gcnt, xa);
    gemm1_mfma<<<dim3((N_NODES + 127) / 128, 2), 256, 0, stream>>>(xa, W1t, b1, h);

    // layer 2: GEMM, then LDS-accumulate mean of t into out
    gemm2_mfma<<<(N_NODES + 127) / 128, 256, 0, stream>>>(h, W2t, b2, t, out);
    acc2_kernel<<<8 * 49, 256, 0, stream>>>(bbuf, gcnt, t, out);
}

// Round 2
// 209.126 us; speedup vs baseline: 5.8702x; 5.8702x over previous
//
#include <hip/hip_runtime.h>

#define N_NODES 50000
#define N_EDGES 800000
#define NFEAT   128
#define NHID    256
#define NCLASS  64

#define ELLCAP  64

// ---- binning geometry (R1's prep proved fast; acc kernels were the regression) ----
#define NBUCK   56
#define BWIDTH  896                      // 7*128: fine 128-node ranges never straddle buckets
#define BCAP    16384                    // mean 14336, +17 sigma headroom
#define BIN_CH  4096                     // edges per bin block
#define BIN_B   ((N_EDGES + BIN_CH - 1) / BIN_CH)   // 196
#define NFINE   ((N_NODES + 127) / 128)  // 391 fine dst ranges
#define FPB     7                        // fine ranges per bucket

#define CVTX_B  ((N_NODES * 32 + 255) / 256)      // 6250
#define CVTW_B  (((65536 + 32768) + 255) / 256)   // 384

typedef unsigned short u16;
typedef unsigned int   u32;
typedef __attribute__((ext_vector_type(8))) short s16x8;
typedef __attribute__((ext_vector_type(4))) float f32x4;

__device__ inline u16 f2bf(float f) {
    u32 u = __float_as_uint(f);
    u32 r = (u + 0x7FFFu + ((u >> 16) & 1u)) >> 16;   // RNE
    return (u16)r;
}
__device__ inline float bflo(u32 v) { return __uint_as_float(v << 16); }
__device__ inline float bfhi(u32 v) { return __uint_as_float(v & 0xFFFF0000u); }

// async global->LDS, 16B per lane; LDS dest must be wave-uniform base + lane*16
#define GLOAD_LDS16(g, l)                                                        \
    __builtin_amdgcn_global_load_lds(                                            \
        (const __attribute__((address_space(1))) u32*)(const void*)(g),          \
        (__attribute__((address_space(3))) u32*)(void*)(l), 16, 0, 0)

// ---------------- fused prep: edge binning | cvt_x | cvt_w ----------------
// Bin block: LDS histogram ranks (cheap) + 56 global reservation atomics.
// Output: bbuf[bucket][pos] = (dst<<16)|src, contiguous per bucket.
__global__ __launch_bounds__(256) void prep_kernel(const float* __restrict__ x,
                                                   const int* __restrict__ ei,
                                                   const float* __restrict__ W1r,
                                                   const float* __restrict__ W1n,
                                                   const float* __restrict__ W2n,
                                                   const float* __restrict__ W2r,
                                                   u16* __restrict__ xa,
                                                   u32* __restrict__ gcnt,
                                                   u32* __restrict__ bbuf,
                                                   u16* __restrict__ W1t,
                                                   u16* __restrict__ W2t) {
    int b = blockIdx.x;
    if (b < BIN_B) {
        __shared__ u32 hist[NBUCK];
        __shared__ u32 base[NBUCK];
        int tid = threadIdx.x;
        if (tid < NBUCK) hist[tid] = 0;
        __syncthreads();
        u32 ek[16]; u32 rk[16]; int bk[16];
        int i0 = b * BIN_CH;
        #pragma unroll
        for (int k = 0; k < 16; ++k) {
            int i = i0 + k * 256 + tid;
            bk[k] = -1;
            if (i < N_EDGES) {
                u32 s = (u32)ei[i];
                u32 d = (u32)ei[N_EDGES + i];
                int bu = (int)(d / BWIDTH);
                ek[k] = (d << 16) | s;      // both < 65536, packing exact
                bk[k] = bu;
                rk[k] = atomicAdd(&hist[bu], 1u);   // LDS rank
            }
        }
        __syncthreads();
        if (tid < NBUCK) base[tid] = atomicAdd(&gcnt[tid], hist[tid]);  // 56 global atomics/block
        __syncthreads();
        #pragma unroll
        for (int k = 0; k < 16; ++k) {
            if (bk[k] >= 0) {
                u32 pos = base[bk[k]] + rk[k];
                if (pos < BCAP) bbuf[((u32)bk[k] << 14) + pos] = ek[k];
            }
        }
    } else if (b < BIN_B + CVTX_B) {
        int idx = (b - BIN_B) * 256 + threadIdx.x;
        if (idx >= N_NODES * 32) return;
        int r  = idx >> 5;
        int c4 = (idx & 31) * 4;
        float4 v = *reinterpret_cast<const float4*>(x + (size_t)r * NFEAT + c4);
        uint2 o;
        o.x = (u32)f2bf(v.x) | ((u32)f2bf(v.y) << 16);
        o.y = (u32)f2bf(v.z) | ((u32)f2bf(v.w) << 16);
        *reinterpret_cast<uint2*>(xa + (size_t)r * 256 + c4) = o;   // cols 0..127 of combined row
    } else {
        int id = (b - BIN_B - CVTX_B) * 256 + threadIdx.x;
        if (id < 65536) {
            int k = id & 255, n = id >> 8;
            float v = (k < NFEAT) ? W1r[(size_t)k * NHID + n]
                                  : W1n[(size_t)(k - NFEAT) * NHID + n];
            W1t[(size_t)n * 256 + k] = f2bf(v);
        } else if (id < 65536 + 32768) {
            int j = id - 65536;
            int k = j & 255, n = j >> 8;
            float v = (n < NCLASS) ? W2n[(size_t)k * NCLASS + n]
                                   : W2r[(size_t)k * NCLASS + (n - NCLASS)];
            W2t[(size_t)n * 256 + k] = f2bf(v);
        }
    }
}

// ---------------- ell_build: bucket -> ELL, zero global atomics ----------------
// One 512-thread block per 128-node fine range. Scans its bucket (~14336 u32,
// L2/L3-resident), ranks hits via LDS atomics on hist[128] (512 B LDS -> full
// occupancy), writes ell (clustered 16 KB region) + cnt.
__global__ __launch_bounds__(512) void ell_build_kernel(const u32* __restrict__ bbuf,
                                                        const u32* __restrict__ gcnt,
                                                        int* __restrict__ cnt,
                                                        u16* __restrict__ ell) {
    __shared__ u32 hist[128];
    int tid = threadIdx.x;
    int f   = blockIdx.x;                 // 0..390
    int cb  = f / FPB;                    // bucket
    int n0  = f * 128;
    if (tid < 128) hist[tid] = 0;
    __syncthreads();
    int m = (int)gcnt[cb]; if (m > BCAP) m = BCAP;
    const u32* bk = bbuf + ((u32)cb << 14);
    int i = tid;
    for (; i + 1536 < m; i += 2048) {
        u32 e0 = bk[i], e1 = bk[i + 512], e2 = bk[i + 1024], e3 = bk[i + 1536];
        u32 d0 = (e0 >> 16) - (u32)n0, d1 = (e1 >> 16) - (u32)n0;
        u32 d2 = (e2 >> 16) - (u32)n0, d3 = (e3 >> 16) - (u32)n0;
        if (d0 < 128u) { u32 p = atomicAdd(&hist[d0], 1u); if (p < ELLCAP) ell[(size_t)(n0 + (int)d0) * ELLCAP + p] = (u16)e0; }
        if (d1 < 128u) { u32 p = atomicAdd(&hist[d1], 1u); if (p < ELLCAP) ell[(size_t)(n0 + (int)d1) * ELLCAP + p] = (u16)e1; }
        if (d2 < 128u) { u32 p = atomicAdd(&hist[d2], 1u); if (p < ELLCAP) ell[(size_t)(n0 + (int)d2) * ELLCAP + p] = (u16)e2; }
        if (d3 < 128u) { u32 p = atomicAdd(&hist[d3], 1u); if (p < ELLCAP) ell[(size_t)(n0 + (int)d3) * ELLCAP + p] = (u16)e3; }
    }
    for (; i < m; i += 512) {
        u32 e = bk[i];
        u32 d = (e >> 16) - (u32)n0;
        if (d < 128u) { u32 p = atomicAdd(&hist[d], 1u); if (p < ELLCAP) ell[(size_t)(n0 + (int)d) * ELLCAP + p] = (u16)e; }
    }
    __syncthreads();
    if (tid < 128) cnt[n0 + tid] = (int)hist[tid];
}

// ---------------- gather 1: xa[n][128:256] = mean of xa[s][0:128] ----------------
// one wave per node, lane = u32 feature pair; 16-deep neighbor unroll (4KB in flight).
// R0-proven: full-occupancy TLP, independent loads.
__global__ __launch_bounds__(256) void gather1_kernel(const int* __restrict__ cnt,
                                                      const u16* __restrict__ ell,
                                                      u16* __restrict__ xa) {
    int gtid = blockIdx.x * 256 + threadIdx.x;
    int node = gtid >> 6;
    if (node >= N_NODES) return;
    int lane = threadIdx.x & 63;
    const u32* xrow = reinterpret_cast<const u32*>(xa);   // row stride 128 u32
    const u16* idx = ell + (size_t)node * ELLCAP;
    int deg = cnt[node];
    if (deg > ELLCAP) deg = ELLCAP;
    float ax = 0.0f, ay = 0.0f;
    int j = 0;
    for (; j + 16 <= deg; j += 16) {
        int s[16]; u32 v[16];
        #pragma unroll
        for (int q = 0; q < 16; ++q) s[q] = idx[j + q];
        #pragma unroll
        for (int q = 0; q < 16; ++q) v[q] = xrow[(size_t)s[q] * 128 + lane];
        #pragma unroll
        for (int q = 0; q < 16; ++q) { ax += bflo(v[q]); ay += bfhi(v[q]); }
    }
    for (; j + 8 <= deg; j += 8) {
        int s[8]; u32 v[8];
        #pragma unroll
        for (int q = 0; q < 8; ++q) s[q] = idx[j + q];
        #pragma unroll
        for (int q = 0; q < 8; ++q) v[q] = xrow[(size_t)s[q] * 128 + lane];
        #pragma unroll
        for (int q = 0; q < 8; ++q) { ax += bflo(v[q]); ay += bfhi(v[q]); }
    }
    for (; j < deg; ++j) {
        u32 v = xrow[(size_t)idx[j] * 128 + lane];
        ax += bflo(v);
        ay += bfhi(v);
    }
    float invd = 1.0f / fmaxf((float)deg, 1.0f);
    u32 packed = (u32)f2bf(ax * invd) | ((u32)f2bf(ay * invd) << 16);
    reinterpret_cast<u32*>(xa + (size_t)node * 256 + 128)[lane] = packed;
}

// ---------------- gather 2: out[n][:] += mean of t[s][:] ----------------
// 2 nodes per wave (t rows = 32 u32), lane&31 = u32 pair; 16-deep unroll.
__global__ __launch_bounds__(256) void gather2_kernel(const int* __restrict__ cnt,
                                                      const u16* __restrict__ ell,
                                                      const u16* __restrict__ t,
                                                      float* __restrict__ out) {
    int gtid = blockIdx.x * 256 + threadIdx.x;
    int wave = gtid >> 6;
    int lane = threadIdx.x & 63;
    int node = wave * 2 + (lane >> 5);
    int l    = lane & 31;
    if (node >= N_NODES) return;
    const u32* trow = reinterpret_cast<const u32*>(t);    // row stride 32 u32
    const u16* idx = ell + (size_t)node * ELLCAP;
    int deg = cnt[node];
    if (deg > ELLCAP) deg = ELLCAP;
    float ax = 0.0f, ay = 0.0f;
    int j = 0;
    for (; j + 16 <= deg; j += 16) {
        int s[16]; u32 v[16];
        #pragma unroll
        for (int q = 0; q < 16; ++q) s[q] = idx[j + q];
        #pragma unroll
        for (int q = 0; q < 16; ++q) v[q] = trow[(size_t)s[q] * 32 + l];
        #pragma unroll
        for (int q = 0; q < 16; ++q) { ax += bflo(v[q]); ay += bfhi(v[q]); }
    }
    for (; j + 8 <= deg; j += 8) {
        int s[8]; u32 v[8];
        #pragma unroll
        for (int q = 0; q < 8; ++q) s[q] = idx[j + q];
        #pragma unroll
        for (int q = 0; q < 8; ++q) v[q] = trow[(size_t)s[q] * 32 + l];
        #pragma unroll
        for (int q = 0; q < 8; ++q) { ax += bflo(v[q]); ay += bfhi(v[q]); }
    }
    for (; j < deg; ++j) {
        u32 v = trow[(size_t)idx[j] * 32 + l];
        ax += bflo(v); ay += bfhi(v);
    }
    float invd = 1.0f / fmaxf((float)deg, 1.0f);
    float* o = out + (size_t)node * NCLASS + l * 2;
    o[0] += ax * invd;
    o[1] += ay * invd;
}

// ---------------- MFMA GEMM 1: h = relu(xa @ W1t^T + b1), bf16 out ----------------
// R12-proven shape: BM=128, BN=128 (dim3 grid), LDS 16 KB, acc[4][4].
__global__ __launch_bounds__(256) void gemm1_mfma(const u16* __restrict__ xa,
                                                  const u16* __restrict__ W1t,
                                                  const float* __restrict__ b1,
                                                  u16* __restrict__ h) {
    __shared__ u16 As[128 * 32];
    __shared__ u16 Bs[128 * 32];
    const int tid = threadIdx.x;
    const int r0 = blockIdx.x * 128;
    const int n0 = blockIdx.y * 128;
    const int wid = tid >> 6, ln = tid & 63;
    const int wm = (wid & 1) * 64, wn = (wid >> 1) * 64;
    const int lr = ln & 15;
    const int lq = ln >> 4;

    f32x4 acc[4][4] = {};

    for (int k0 = 0; k0 < 256; k0 += 32) {
        #pragma unroll
        for (int it = 0; it < 2; ++it) {
            int c   = it * 256 + tid;      // chunk 0..511; LDS dest = c*16 B (lane-contiguous)
            int row = c >> 2;
            int ko  = (c & 3) * 8;
            GLOAD_LDS16(xa  + (size_t)(r0 + row) * 256 + k0 + ko, As + c * 8);
            GLOAD_LDS16(W1t + (size_t)(n0 + row) * 256 + k0 + ko, Bs + c * 8);
        }
        __syncthreads();

        s16x8 af[4], bf[4];
        #pragma unroll
        for (int i = 0; i < 4; ++i)
            af[i] = *reinterpret_cast<const s16x8*>(As + (wm + i * 16 + lr) * 32 + lq * 8);
        #pragma unroll
        for (int j = 0; j < 4; ++j)
            bf[j] = *reinterpret_cast<const s16x8*>(Bs + (wn + j * 16 + lr) * 32 + lq * 8);
        #pragma unroll
        for (int i = 0; i < 4; ++i)
            #pragma unroll
            for (int j = 0; j < 4; ++j)
                acc[i][j] = __builtin_amdgcn_mfma_f32_16x16x32_bf16(af[i], bf[j], acc[i][j], 0, 0, 0);
        __syncthreads();
    }

    #pragma unroll
    for (int i = 0; i < 4; ++i) {
        #pragma unroll
        for (int j = 0; j < 4; ++j) {
            int col = n0 + wn + j * 16 + lr;
            float bias = b1[col];
            #pragma unroll
            for (int r = 0; r < 4; ++r) {
                int row = r0 + wm + i * 16 + lq * 4 + r;
                if (row < N_NODES)
                    h[(size_t)row * 256 + col] = f2bf(fmaxf(acc[i][j][r] + bias, 0.0f));
            }
        }
    }
}

// ---------------- MFMA GEMM 2 (fused): cols 0..63 -> t (bf16), 64..127 -> out+b2 (f32) ----------------
__global__ __launch_bounds__(256) void gemm2_mfma(const u16* __restrict__ h,
                                                  const u16* __restrict__ W2t,
                                                  const float* __restrict__ b2,
                                                  u16* __restrict__ t,
                                                  float* __restrict__ out) {
    __shared__ u16 As[128 * 32];
    __shared__ u16 Bs[128 * 32];
    const int tid = threadIdx.x;
    const int r0 = blockIdx.x * 128;
    const int wid = tid >> 6, ln = tid & 63;
    const int wm = (wid & 1) * 64, wn = (wid >> 1) * 64;
    const int lr = ln & 15;
    const int lq = ln >> 4;

    f32x4 acc[4][4] = {};

    for (int k0 = 0; k0 < 256; k0 += 32) {
        #pragma unroll
        for (int it = 0; it < 2; ++it) {
            int c   = it * 256 + tid;
            int row = c >> 2;
            int ko  = (c & 3) * 8;
            GLOAD_LDS16(h   + (size_t)(r0 + row) * 256 + k0 + ko, As + c * 8);
            GLOAD_LDS16(W2t + (size_t)row * 256 + k0 + ko,        Bs + c * 8);
        }
        __syncthreads();

        s16x8 af[4], bf[4];
        #pragma unroll
        for (int i = 0; i < 4; ++i)
            af[i] = *reinterpret_cast<const s16x8*>(As + (wm + i * 16 + lr) * 32 + lq * 8);
        #pragma unroll
        for (int j = 0; j < 4; ++j)
            bf[j] = *reinterpret_cast<const s16x8*>(Bs + (wn + j * 16 + lr) * 32 + lq * 8);
        #pragma unroll
        for (int i = 0; i < 4; ++i)
            #pragma unroll
            for (int j = 0; j < 4; ++j)
                acc[i][j] = __builtin_amdgcn_mfma_f32_16x16x32_bf16(af[i], bf[j], acc[i][j], 0, 0, 0);
        __syncthreads();
    }

    #pragma unroll
    for (int i = 0; i < 4; ++i) {
        #pragma unroll
        for (int j = 0; j < 4; ++j) {
            int col = wn + j * 16 + lr;   // 0..127
            #pragma unroll
            for (int r = 0; r < 4; ++r) {
                int row = r0 + wm + i * 16 + lq * 4 + r;
                if (row >= N_NODES) continue;
                if (col < NCLASS) {
                    t[(size_t)row * NCLASS + col] = f2bf(acc[i][j][r]);
                } else {
                    int c = col - NCLASS;
                    out[(size_t)row * NCLASS + c] = acc[i][j][r] + b2[c];
                }
            }
        }
    }
}

extern "C" void kernel_launch(void* const* d_in, const int* in_sizes, int n_in,
                              void* d_out, int out_size, void* d_ws, size_t ws_size,
                              hipStream_t stream) {
    const float* x    = (const float*)d_in[0];
    const int*   ei   = (const int*)d_in[1];
    const float* W1n  = (const float*)d_in[2];
    const float* W1r  = (const float*)d_in[3];
    const float* b1   = (const float*)d_in[4];
    const float* W2n  = (const float*)d_in[5];
    const float* W2r  = (const float*)d_in[6];
    const float* b2   = (const float*)d_in[7];
    float* out = (float*)d_out;

    // workspace: gcnt u32[64] | bbuf u32[56<<14] | cnt int[50048] | ell u16[50000*64]
    //          | xa u16[50000*256] | h u16[50000*256] | t u16[50000*64] | W1t | W2t
    u32* gcnt = (u32*)d_ws;
    u32* bbuf = gcnt + 64;
    int* cnt  = (int*)(bbuf + ((size_t)NBUCK << 14));
    u16* ell  = (u16*)(cnt + 50048);
    u16* xa   = ell + (size_t)N_NODES * ELLCAP;
    u16* h    = xa + (size_t)N_NODES * 256;
    u16* t    = h  + (size_t)N_NODES * 256;
    u16* W1t  = t  + (size_t)N_NODES * 64;
    u16* W2t  = W1t + 65536;

    hipMemsetAsync(gcnt, 0, 64 * sizeof(u32), stream);

    // bin edges + bf16 converts (one dispatch), then atomic-free ELL build
    prep_kernel<<<BIN_B + CVTX_B + CVTW_B, 256, 0, stream>>>(
        x, ei, W1r, W1n, W2n, W2r, xa, gcnt, bbuf, W1t, W2t);
    ell_build_kernel<<<NFINE, 512, 0, stream>>>(bbuf, gcnt, cnt, ell);

    // layer 1 (separate gather: needs full-occupancy TLP — R11 post-mortem)
    gather1_kernel<<<(N_NODES * 64 + 255) / 256, 256, 0, stream>>>(cnt, ell, xa);
    gemm1_mfma<<<dim3((N_NODES + 127) / 128, 2), 256, 0, stream>>>(xa, W1t, b1, h);

    // layer 2
    gemm2_mfma<<<(N_NODES + 127) / 128, 256, 0, stream>>>(h, W2t, b2, t, out);
    gather2_kernel<<<(N_NODES * 32 + 255) / 256, 256, 0, stream>>>(cnt, ell, t, out);
}

// Round 3
// 204.150 us; speedup vs baseline: 6.0133x; 1.0244x over previous
//
#include <hip/hip_runtime.h>

#define N_NODES 50000
#define N_EDGES 800000
#define NFEAT   128
#define NHID    256
#define NCLASS  64

#define ELLCAP  64

// ---- binning geometry (R2-proven: 56 reservation atomics/block replaces 800k pos atomics) ----
#define NBUCK   56
#define BWIDTH  896                      // 7*128: fine 128-node ranges never straddle buckets
#define BCAP    16384                    // mean 14336, +17 sigma headroom
#define BIN_CH  4096                     // edges per bin block
#define BIN_B   ((N_EDGES + BIN_CH - 1) / BIN_CH)   // 196
#define NFINE   ((N_NODES + 127) / 128)  // 391 fine dst ranges
#define FPB     7                        // fine ranges per bucket

#define CVTX_B  ((N_NODES * 32 + 255) / 256)      // 6250
#define CVTW_B  (((65536 + 32768) + 255) / 256)   // 384

typedef unsigned short u16;
typedef unsigned int   u32;
typedef __attribute__((ext_vector_type(8))) short s16x8;
typedef __attribute__((ext_vector_type(4))) float f32x4;

__device__ inline u16 f2bf(float f) {
    u32 u = __float_as_uint(f);
    u32 r = (u + 0x7FFFu + ((u >> 16) & 1u)) >> 16;   // RNE
    return (u16)r;
}
__device__ inline float bflo(u32 v) { return __uint_as_float(v << 16); }
__device__ inline float bfhi(u32 v) { return __uint_as_float(v & 0xFFFF0000u); }

// async global->LDS, 16B per lane; LDS dest must be wave-uniform base + lane*16
#define GLOAD_LDS16(g, l)                                                        \
    __builtin_amdgcn_global_load_lds(                                            \
        (const __attribute__((address_space(1))) u32*)(const void*)(g),          \
        (__attribute__((address_space(3))) u32*)(void*)(l), 16, 0, 0)

// ---------------- fused prep: edge binning | cvt_x | cvt_w ----------------
__global__ __launch_bounds__(256) void prep_kernel(const float* __restrict__ x,
                                                   const int* __restrict__ ei,
                                                   const float* __restrict__ W1r,
                                                   const float* __restrict__ W1n,
                                                   const float* __restrict__ W2n,
                                                   const float* __restrict__ W2r,
                                                   u16* __restrict__ xa,
                                                   u32* __restrict__ gcnt,
                                                   u32* __restrict__ bbuf,
                                                   u16* __restrict__ W1t,
                                                   u16* __restrict__ W2t) {
    int b = blockIdx.x;
    if (b < BIN_B) {
        __shared__ u32 hist[NBUCK];
        __shared__ u32 base[NBUCK];
        int tid = threadIdx.x;
        if (tid < NBUCK) hist[tid] = 0;
        __syncthreads();
        u32 ek[16]; u32 rk[16]; int bk[16];
        int i0 = b * BIN_CH;
        #pragma unroll
        for (int k = 0; k < 16; ++k) {
            int i = i0 + k * 256 + tid;
            bk[k] = -1;
            if (i < N_EDGES) {
                u32 s = (u32)ei[i];
                u32 d = (u32)ei[N_EDGES + i];
                int bu = (int)(d / BWIDTH);
                ek[k] = (d << 16) | s;      // both < 65536, packing exact
                bk[k] = bu;
                rk[k] = atomicAdd(&hist[bu], 1u);   // LDS rank
            }
        }
        __syncthreads();
        if (tid < NBUCK) base[tid] = atomicAdd(&gcnt[tid], hist[tid]);  // 56 global atomics/block
        __syncthreads();
        #pragma unroll
        for (int k = 0; k < 16; ++k) {
            if (bk[k] >= 0) {
                u32 pos = base[bk[k]] + rk[k];
                if (pos < BCAP) bbuf[((u32)bk[k] << 14) + pos] = ek[k];
            }
        }
    } else if (b < BIN_B + CVTX_B) {
        int idx = (b - BIN_B) * 256 + threadIdx.x;
        if (idx >= N_NODES * 32) return;
        int r  = idx >> 5;
        int c4 = (idx & 31) * 4;
        float4 v = *reinterpret_cast<const float4*>(x + (size_t)r * NFEAT + c4);
        uint2 o;
        o.x = (u32)f2bf(v.x) | ((u32)f2bf(v.y) << 16);
        o.y = (u32)f2bf(v.z) | ((u32)f2bf(v.w) << 16);
        *reinterpret_cast<uint2*>(xa + (size_t)r * 256 + c4) = o;   // cols 0..127 of combined row
    } else {
        int id = (b - BIN_B - CVTX_B) * 256 + threadIdx.x;
        if (id < 65536) {
            int k = id & 255, n = id >> 8;
            float v = (k < NFEAT) ? W1r[(size_t)k * NHID + n]
                                  : W1n[(size_t)(k - NFEAT) * NHID + n];
            W1t[(size_t)n * 256 + k] = f2bf(v);
        } else if (id < 65536 + 32768) {
            int j = id - 65536;
            int k = j & 255, n = j >> 8;
            float v = (n < NCLASS) ? W2n[(size_t)k * NCLASS + n]
                                   : W2r[(size_t)k * NCLASS + (n - NCLASS)];
            W2t[(size_t)n * 256 + k] = f2bf(v);
        }
    }
}

// ---------------- ell_build: bucket -> ELL, zero global atomics (R2-proven) ----------------
__global__ __launch_bounds__(512) void ell_build_kernel(const u32* __restrict__ bbuf,
                                                        const u32* __restrict__ gcnt,
                                                        int* __restrict__ cnt,
                                                        u16* __restrict__ ell) {
    __shared__ u32 hist[128];
    int tid = threadIdx.x;
    int f   = blockIdx.x;                 // 0..390
    int cb  = f / FPB;                    // bucket
    int n0  = f * 128;
    if (tid < 128) hist[tid] = 0;
    __syncthreads();
    int m = (int)gcnt[cb]; if (m > BCAP) m = BCAP;
    const u32* bk = bbuf + ((u32)cb << 14);
    int i = tid;
    for (; i + 1536 < m; i += 2048) {
        u32 e0 = bk[i], e1 = bk[i + 512], e2 = bk[i + 1024], e3 = bk[i + 1536];
        u32 d0 = (e0 >> 16) - (u32)n0, d1 = (e1 >> 16) - (u32)n0;
        u32 d2 = (e2 >> 16) - (u32)n0, d3 = (e3 >> 16) - (u32)n0;
        if (d0 < 128u) { u32 p = atomicAdd(&hist[d0], 1u); if (p < ELLCAP) ell[(size_t)(n0 + (int)d0) * ELLCAP + p] = (u16)e0; }
        if (d1 < 128u) { u32 p = atomicAdd(&hist[d1], 1u); if (p < ELLCAP) ell[(size_t)(n0 + (int)d1) * ELLCAP + p] = (u16)e1; }
        if (d2 < 128u) { u32 p = atomicAdd(&hist[d2], 1u); if (p < ELLCAP) ell[(size_t)(n0 + (int)d2) * ELLCAP + p] = (u16)e2; }
        if (d3 < 128u) { u32 p = atomicAdd(&hist[d3], 1u); if (p < ELLCAP) ell[(size_t)(n0 + (int)d3) * ELLCAP + p] = (u16)e3; }
    }
    for (; i < m; i += 512) {
        u32 e = bk[i];
        u32 d = (e >> 16) - (u32)n0;
        if (d < 128u) { u32 p = atomicAdd(&hist[d], 1u); if (p < ELLCAP) ell[(size_t)(n0 + (int)d) * ELLCAP + p] = (u16)e; }
    }
    __syncthreads();
    if (tid < 128) cnt[n0 + tid] = (int)hist[tid];
}

// ---------------- gather 1: xa[n][128:256] = mean of xa[s][0:128] ----------------
// R3: 16B/lane uint4 loads. 4 groups x 16 lanes; one uint4 instr = 4 full 256B rows.
// Per deg-16 node: 4 row-load + 4 idx-load VMEM (was 32). Cross-group shfl reduce.
#define ACC8(v)                                                      \
    do { a[0] += bflo((v).x); a[1] += bfhi((v).x);                   \
         a[2] += bflo((v).y); a[3] += bfhi((v).y);                   \
         a[4] += bflo((v).z); a[5] += bfhi((v).z);                   \
         a[6] += bflo((v).w); a[7] += bfhi((v).w); } while (0)

__global__ __launch_bounds__(256) void gather1_kernel(const int* __restrict__ cnt,
                                                      const u16* __restrict__ ell,
                                                      u16* __restrict__ xa) {
    int gtid = blockIdx.x * 256 + threadIdx.x;
    int node = gtid >> 6;
    if (node >= N_NODES) return;
    int lane = threadIdx.x & 63;
    int g = lane >> 4, lr = lane & 15;                    // 4 groups x 16 lanes
    const u32* xrow = reinterpret_cast<const u32*>(xa);   // row stride 128 u32
    const u16* idx = ell + (size_t)node * ELLCAP;
    int deg = cnt[node];
    if (deg > ELLCAP) deg = ELLCAP;
    float a[8] = {};                                      // features 8*lr .. 8*lr+7
    int j = 0;
    for (; j + 16 <= deg; j += 16) {
        int s0 = idx[j + g], s1 = idx[j + 4 + g], s2 = idx[j + 8 + g], s3 = idx[j + 12 + g];
        uint4 v0 = *reinterpret_cast<const uint4*>(xrow + (size_t)s0 * 128 + lr * 4);
        uint4 v1 = *reinterpret_cast<const uint4*>(xrow + (size_t)s1 * 128 + lr * 4);
        uint4 v2 = *reinterpret_cast<const uint4*>(xrow + (size_t)s2 * 128 + lr * 4);
        uint4 v3 = *reinterpret_cast<const uint4*>(xrow + (size_t)s3 * 128 + lr * 4);
        ACC8(v0); ACC8(v1); ACC8(v2); ACC8(v3);
    }
    for (; j + 4 <= deg; j += 4) {
        int s0 = idx[j + g];
        uint4 v0 = *reinterpret_cast<const uint4*>(xrow + (size_t)s0 * 128 + lr * 4);
        ACC8(v0);
    }
    if (g < deg - j) {                                    // tail 0..3, predicated
        int s0 = idx[j + g];
        uint4 v0 = *reinterpret_cast<const uint4*>(xrow + (size_t)s0 * 128 + lr * 4);
        ACC8(v0);
    }
    #pragma unroll
    for (int k = 0; k < 8; ++k) {                         // reduce over 4 groups
        a[k] += __shfl_xor(a[k], 16);
        a[k] += __shfl_xor(a[k], 32);
    }
    if (g == 0) {
        float invd = 1.0f / fmaxf((float)deg, 1.0f);
        uint4 pk;
        pk.x = (u32)f2bf(a[0] * invd) | ((u32)f2bf(a[1] * invd) << 16);
        pk.y = (u32)f2bf(a[2] * invd) | ((u32)f2bf(a[3] * invd) << 16);
        pk.z = (u32)f2bf(a[4] * invd) | ((u32)f2bf(a[5] * invd) << 16);
        pk.w = (u32)f2bf(a[6] * invd) | ((u32)f2bf(a[7] * invd) << 16);
        *reinterpret_cast<uint4*>(reinterpret_cast<u32*>(xa) + (size_t)node * 128 + 64 + lr * 4) = pk;
    }
}

// ---------------- gather 2: out[n][:] += mean of t[s][:] ----------------
// R3: one node per wave; 8 groups x 8 lanes; uint4 instr = 8 full 128B rows.
__global__ __launch_bounds__(256) void gather2_kernel(const int* __restrict__ cnt,
                                                      const u16* __restrict__ ell,
                                                      const u16* __restrict__ t,
                                                      float* __restrict__ out) {
    int gtid = blockIdx.x * 256 + threadIdx.x;
    int node = gtid >> 6;
    if (node >= N_NODES) return;
    int lane = threadIdx.x & 63;
    int g = lane >> 3, lr = lane & 7;                     // 8 groups x 8 lanes
    const u32* trow = reinterpret_cast<const u32*>(t);    // row stride 32 u32
    const u16* idx = ell + (size_t)node * ELLCAP;
    int deg = cnt[node];
    if (deg > ELLCAP) deg = ELLCAP;
    float a[8] = {};                                      // features 8*lr .. 8*lr+7
    int j = 0;
    for (; j + 16 <= deg; j += 16) {
        int s0 = idx[j + g], s1 = idx[j + 8 + g];
        uint4 v0 = *reinterpret_cast<const uint4*>(trow + (size_t)s0 * 32 + lr * 4);
        uint4 v1 = *reinterpret_cast<const uint4*>(trow + (size_t)s1 * 32 + lr * 4);
        ACC8(v0); ACC8(v1);
    }
    for (; j + 8 <= deg; j += 8) {
        int s0 = idx[j + g];
        uint4 v0 = *reinterpret_cast<const uint4*>(trow + (size_t)s0 * 32 + lr * 4);
        ACC8(v0);
    }
    if (g < deg - j) {                                    // tail 0..7, predicated
        int s0 = idx[j + g];
        uint4 v0 = *reinterpret_cast<const uint4*>(trow + (size_t)s0 * 32 + lr * 4);
        ACC8(v0);
    }
    #pragma unroll
    for (int k = 0; k < 8; ++k) {                         // reduce over 8 groups
        a[k] += __shfl_xor(a[k], 8);
        a[k] += __shfl_xor(a[k], 16);
        a[k] += __shfl_xor(a[k], 32);
    }
    if (g == 0) {
        float invd = 1.0f / fmaxf((float)deg, 1.0f);
        float* o = out + (size_t)node * NCLASS + lr * 8;
        float4 o0 = *reinterpret_cast<float4*>(o);
        float4 o1 = *reinterpret_cast<float4*>(o + 4);
        o0.x += a[0] * invd; o0.y += a[1] * invd; o0.z += a[2] * invd; o0.w += a[3] * invd;
        o1.x += a[4] * invd; o1.y += a[5] * invd; o1.z += a[6] * invd; o1.w += a[7] * invd;
        *reinterpret_cast<float4*>(o) = o0;
        *reinterpret_cast<float4*>(o + 4) = o1;
    }
}

// ---------------- MFMA GEMM 1: h = relu(xa @ W1t^T + b1), bf16 out ----------------
__global__ __launch_bounds__(256) void gemm1_mfma(const u16* __restrict__ xa,
                                                  const u16* __restrict__ W1t,
                                                  const float* __restrict__ b1,
                                                  u16* __restrict__ h) {
    __shared__ u16 As[128 * 32];
    __shared__ u16 Bs[128 * 32];
    const int tid = threadIdx.x;
    const int r0 = blockIdx.x * 128;
    const int n0 = blockIdx.y * 128;
    const int wid = tid >> 6, ln = tid & 63;
    const int wm = (wid & 1) * 64, wn = (wid >> 1) * 64;
    const int lr = ln & 15;
    const int lq = ln >> 4;

    f32x4 acc[4][4] = {};

    for (int k0 = 0; k0 < 256; k0 += 32) {
        #pragma unroll
        for (int it = 0; it < 2; ++it) {
            int c   = it * 256 + tid;      // chunk 0..511; LDS dest = c*16 B (lane-contiguous)
            int row = c >> 2;
            int ko  = (c & 3) * 8;
            GLOAD_LDS16(xa  + (size_t)(r0 + row) * 256 + k0 + ko, As + c * 8);
            GLOAD_LDS16(W1t + (size_t)(n0 + row) * 256 + k0 + ko, Bs + c * 8);
        }
        __syncthreads();

        s16x8 af[4], bf[4];
        #pragma unroll
        for (int i = 0; i < 4; ++i)
            af[i] = *reinterpret_cast<const s16x8*>(As + (wm + i * 16 + lr) * 32 + lq * 8);
        #pragma unroll
        for (int j = 0; j < 4; ++j)
            bf[j] = *reinterpret_cast<const s16x8*>(Bs + (wn + j * 16 + lr) * 32 + lq * 8);
        #pragma unroll
        for (int i = 0; i < 4; ++i)
            #pragma unroll
            for (int j = 0; j < 4; ++j)
                acc[i][j] = __builtin_amdgcn_mfma_f32_16x16x32_bf16(af[i], bf[j], acc[i][j], 0, 0, 0);
        __syncthreads();
    }

    #pragma unroll
    for (int i = 0; i < 4; ++i) {
        #pragma unroll
        for (int j = 0; j < 4; ++j) {
            int col = n0 + wn + j * 16 + lr;
            float bias = b1[col];
            #pragma unroll
            for (int r = 0; r < 4; ++r) {
                int row = r0 + wm + i * 16 + lq * 4 + r;
                if (row < N_NODES)
                    h[(size_t)row * 256 + col] = f2bf(fmaxf(acc[i][j][r] + bias, 0.0f));
            }
        }
    }
}

// ---------------- MFMA GEMM 2 (fused): cols 0..63 -> t (bf16), 64..127 -> out+b2 (f32) ----------------
__global__ __launch_bounds__(256) void gemm2_mfma(const u16* __restrict__ h,
                                                  const u16* __restrict__ W2t,
                                                  const float* __restrict__ b2,
                                                  u16* __restrict__ t,
                                                  float* __restrict__ out) {
    __shared__ u16 As[128 * 32];
    __shared__ u16 Bs[128 * 32];
    const int tid = threadIdx.x;
    const int r0 = blockIdx.x * 128;
    const int wid = tid >> 6, ln = tid & 63;
    const int wm = (wid & 1) * 64, wn = (wid >> 1) * 64;
    const int lr = ln & 15;
    const int lq = ln >> 4;

    f32x4 acc[4][4] = {};

    for (int k0 = 0; k0 < 256; k0 += 32) {
        #pragma unroll
        for (int it = 0; it < 2; ++it) {
            int c   = it * 256 + tid;
            int row = c >> 2;
            int ko  = (c & 3) * 8;
            GLOAD_LDS16(h   + (size_t)(r0 + row) * 256 + k0 + ko, As + c * 8);
            GLOAD_LDS16(W2t + (size_t)row * 256 + k0 + ko,        Bs + c * 8);
        }
        __syncthreads();

        s16x8 af[4], bf[4];
        #pragma unroll
        for (int i = 0; i < 4; ++i)
            af[i] = *reinterpret_cast<const s16x8*>(As + (wm + i * 16 + lr) * 32 + lq * 8);
        #pragma unroll
        for (int j = 0; j < 4; ++j)
            bf[j] = *reinterpret_cast<const s16x8*>(Bs + (wn + j * 16 + lr) * 32 + lq * 8);
        #pragma unroll
        for (int i = 0; i < 4; ++i)
            #pragma unroll
            for (int j = 0; j < 4; ++j)
                acc[i][j] = __builtin_amdgcn_mfma_f32_16x16x32_bf16(af[i], bf[j], acc[i][j], 0, 0, 0);
        __syncthreads();
    }

    #pragma unroll
    for (int i = 0; i < 4; ++i) {
        #pragma unroll
        for (int j = 0; j < 4; ++j) {
            int col = wn + j * 16 + lr;   // 0..127
            #pragma unroll
            for (int r = 0; r < 4; ++r) {
                int row = r0 + wm + i * 16 + lq * 4 + r;
                if (row >= N_NODES) continue;
                if (col < NCLASS) {
                    t[(size_t)row * NCLASS + col] = f2bf(acc[i][j][r]);
                } else {
                    int c = col - NCLASS;
                    out[(size_t)row * NCLASS + c] = acc[i][j][r] + b2[c];
                }
            }
        }
    }
}

extern "C" void kernel_launch(void* const* d_in, const int* in_sizes, int n_in,
                              void* d_out, int out_size, void* d_ws, size_t ws_size,
                              hipStream_t stream) {
    const float* x    = (const float*)d_in[0];
    const int*   ei   = (const int*)d_in[1];
    const float* W1n  = (const float*)d_in[2];
    const float* W1r  = (const float*)d_in[3];
    const float* b1   = (const float*)d_in[4];
    const float* W2n  = (const float*)d_in[5];
    const float* W2r  = (const float*)d_in[6];
    const float* b2   = (const float*)d_in[7];
    float* out = (float*)d_out;

    // workspace: gcnt u32[64] | bbuf u32[56<<14] | cnt int[50048] | ell u16[50000*64]
    //          | xa u16[50000*256] | h u16[50000*256] | t u16[50000*64] | W1t | W2t
    u32* gcnt = (u32*)d_ws;
    u32* bbuf = gcnt + 64;
    int* cnt  = (int*)(bbuf + ((size_t)NBUCK << 14));
    u16* ell  = (u16*)(cnt + 50048);
    u16* xa   = ell + (size_t)N_NODES * ELLCAP;
    u16* h    = xa + (size_t)N_NODES * 256;
    u16* t    = h  + (size_t)N_NODES * 256;
    u16* W1t  = t  + (size_t)N_NODES * 64;
    u16* W2t  = W1t + 65536;

    hipMemsetAsync(gcnt, 0, 64 * sizeof(u32), stream);

    // bin edges + bf16 converts (one dispatch), then atomic-free ELL build
    prep_kernel<<<BIN_B + CVTX_B + CVTW_B, 256, 0, stream>>>(
        x, ei, W1r, W1n, W2n, W2r, xa, gcnt, bbuf, W1t, W2t);
    ell_build_kernel<<<NFINE, 512, 0, stream>>>(bbuf, gcnt, cnt, ell);

    // layer 1
    gather1_kernel<<<(N_NODES * 64 + 255) / 256, 256, 0, stream>>>(cnt, ell, xa);
    gemm1_mfma<<<dim3((N_NODES + 127) / 128, 2), 256, 0, stream>>>(xa, W1t, b1, h);

    // layer 2
    gemm2_mfma<<<(N_NODES + 127) / 128, 256, 0, stream>>>(h, W2t, b2, t, out);
    gather2_kernel<<<(N_NODES * 64 + 255) / 256, 256, 0, stream>>>(cnt, ell, t, out);
}

// Round 4
// 191.311 us; speedup vs baseline: 6.4168x; 1.0671x over previous
//
#include <hip/hip_runtime.h>

#define N_NODES 50000
#define N_EDGES 800000
#define NFEAT   128
#define NHID    256
#define NCLASS  64

#define ELLCAP  64

// ---- binning geometry (R2-proven: 56 reservation atomics/block replaces 800k pos atomics) ----
#define NBUCK   56
#define BWIDTH  896                      // 7*128: fine 128-node ranges never straddle buckets
#define BCAP    16384                    // mean 14336, +17 sigma headroom
#define BIN_CH  4096                     // edges per bin block
#define BIN_B   ((N_EDGES + BIN_CH - 1) / BIN_CH)   // 196
#define NFINE   ((N_NODES + 127) / 128)  // 391 fine dst ranges
#define FPB     7                        // fine ranges per bucket

#define CVTX_B  ((N_NODES * 32 + 255) / 256)      // 6250
#define CVTW_B  (((65536 + 32768) + 255) / 256)   // 384

typedef unsigned short u16;
typedef unsigned int   u32;
typedef __attribute__((ext_vector_type(8))) short s16x8;
typedef __attribute__((ext_vector_type(4))) float f32x4;

__device__ inline u16 f2bf(float f) {
    u32 u = __float_as_uint(f);
    u32 r = (u + 0x7FFFu + ((u >> 16) & 1u)) >> 16;   // RNE
    return (u16)r;
}
__device__ inline float bflo(u32 v) { return __uint_as_float(v << 16); }
__device__ inline float bfhi(u32 v) { return __uint_as_float(v & 0xFFFF0000u); }

// async global->LDS, 16B per lane; LDS dest must be wave-uniform base + lane*16
#define GLOAD_LDS16(g, l)                                                        \
    __builtin_amdgcn_global_load_lds(                                            \
        (const __attribute__((address_space(1))) u32*)(const void*)(g),          \
        (__attribute__((address_space(3))) u32*)(void*)(l), 16, 0, 0)

// ---------------- fused prep: edge binning | cvt_x | cvt_w ----------------
__global__ __launch_bounds__(256) void prep_kernel(const float* __restrict__ x,
                                                   const int* __restrict__ ei,
                                                   const float* __restrict__ W1r,
                                                   const float* __restrict__ W1n,
                                                   const float* __restrict__ W2n,
                                                   const float* __restrict__ W2r,
                                                   u16* __restrict__ xa,
                                                   u32* __restrict__ gcnt,
                                                   u32* __restrict__ bbuf,
                                                   u16* __restrict__ W1t,
                                                   u16* __restrict__ W2t) {
    int b = blockIdx.x;
    if (b < BIN_B) {
        __shared__ u32 hist[NBUCK];
        __shared__ u32 base[NBUCK];
        int tid = threadIdx.x;
        if (tid < NBUCK) hist[tid] = 0;
        __syncthreads();
        u32 ek[16]; u32 rk[16]; int bk[16];
        int i0 = b * BIN_CH;
        #pragma unroll
        for (int k = 0; k < 16; ++k) {
            int i = i0 + k * 256 + tid;
            bk[k] = -1;
            if (i < N_EDGES) {
                u32 s = (u32)ei[i];
                u32 d = (u32)ei[N_EDGES + i];
                int bu = (int)(d / BWIDTH);
                ek[k] = (d << 16) | s;      // both < 65536, packing exact
                bk[k] = bu;
                rk[k] = atomicAdd(&hist[bu], 1u);   // LDS rank
            }
        }
        __syncthreads();
        if (tid < NBUCK) base[tid] = atomicAdd(&gcnt[tid], hist[tid]);  // 56 global atomics/block
        __syncthreads();
        #pragma unroll
        for (int k = 0; k < 16; ++k) {
            if (bk[k] >= 0) {
                u32 pos = base[bk[k]] + rk[k];
                if (pos < BCAP) bbuf[((u32)bk[k] << 14) + pos] = ek[k];
            }
        }
    } else if (b < BIN_B + CVTX_B) {
        int idx = (b - BIN_B) * 256 + threadIdx.x;
        if (idx >= N_NODES * 32) return;
        int r  = idx >> 5;
        int c4 = (idx & 31) * 4;
        float4 v = *reinterpret_cast<const float4*>(x + (size_t)r * NFEAT + c4);
        uint2 o;
        o.x = (u32)f2bf(v.x) | ((u32)f2bf(v.y) << 16);
        o.y = (u32)f2bf(v.z) | ((u32)f2bf(v.w) << 16);
        *reinterpret_cast<uint2*>(xa + (size_t)r * 256 + c4) = o;   // cols 0..127 of combined row
    } else {
        int id = (b - BIN_B - CVTX_B) * 256 + threadIdx.x;
        if (id < 65536) {
            int k = id & 255, n = id >> 8;
            float v = (k < NFEAT) ? W1r[(size_t)k * NHID + n]
                                  : W1n[(size_t)(k - NFEAT) * NHID + n];
            W1t[(size_t)n * 256 + k] = f2bf(v);
        } else if (id < 65536 + 32768) {
            int j = id - 65536;
            int k = j & 255, n = j >> 8;
            float v = (n < NCLASS) ? W2n[(size_t)k * NCLASS + n]
                                   : W2r[(size_t)k * NCLASS + (n - NCLASS)];
            W2t[(size_t)n * 256 + k] = f2bf(v);
        }
    }
}

// ---------------- ell_build: bucket -> ELL, zero global atomics (R2-proven) ----------------
__global__ __launch_bounds__(512) void ell_build_kernel(const u32* __restrict__ bbuf,
                                                        const u32* __restrict__ gcnt,
                                                        int* __restrict__ cnt,
                                                        u16* __restrict__ ell) {
    __shared__ u32 hist[128];
    int tid = threadIdx.x;
    int f   = blockIdx.x;                 // 0..390
    int cb  = f / FPB;                    // bucket
    int n0  = f * 128;
    if (tid < 128) hist[tid] = 0;
    __syncthreads();
    int m = (int)gcnt[cb]; if (m > BCAP) m = BCAP;
    const u32* bk = bbuf + ((u32)cb << 14);
    int i = tid;
    for (; i + 1536 < m; i += 2048) {
        u32 e0 = bk[i], e1 = bk[i + 512], e2 = bk[i + 1024], e3 = bk[i + 1536];
        u32 d0 = (e0 >> 16) - (u32)n0, d1 = (e1 >> 16) - (u32)n0;
        u32 d2 = (e2 >> 16) - (u32)n0, d3 = (e3 >> 16) - (u32)n0;
        if (d0 < 128u) { u32 p = atomicAdd(&hist[d0], 1u); if (p < ELLCAP) ell[(size_t)(n0 + (int)d0) * ELLCAP + p] = (u16)e0; }
        if (d1 < 128u) { u32 p = atomicAdd(&hist[d1], 1u); if (p < ELLCAP) ell[(size_t)(n0 + (int)d1) * ELLCAP + p] = (u16)e1; }
        if (d2 < 128u) { u32 p = atomicAdd(&hist[d2], 1u); if (p < ELLCAP) ell[(size_t)(n0 + (int)d2) * ELLCAP + p] = (u16)e2; }
        if (d3 < 128u) { u32 p = atomicAdd(&hist[d3], 1u); if (p < ELLCAP) ell[(size_t)(n0 + (int)d3) * ELLCAP + p] = (u16)e3; }
    }
    for (; i < m; i += 512) {
        u32 e = bk[i];
        u32 d = (e >> 16) - (u32)n0;
        if (d < 128u) { u32 p = atomicAdd(&hist[d], 1u); if (p < ELLCAP) ell[(size_t)(n0 + (int)d) * ELLCAP + p] = (u16)e; }
    }
    __syncthreads();
    if (tid < 128) cnt[n0 + tid] = (int)hist[tid];
}

// ---------------- gather 1: xa[n][128:256] = mean of xa[s][0:128] (R3-proven) ----------------
#define ACC8(v)                                                      \
    do { a[0] += bflo((v).x); a[1] += bfhi((v).x);                   \
         a[2] += bflo((v).y); a[3] += bfhi((v).y);                   \
         a[4] += bflo((v).z); a[5] += bfhi((v).z);                   \
         a[6] += bflo((v).w); a[7] += bfhi((v).w); } while (0)

__global__ __launch_bounds__(256) void gather1_kernel(const int* __restrict__ cnt,
                                                      const u16* __restrict__ ell,
                                                      u16* __restrict__ xa) {
    int gtid = blockIdx.x * 256 + threadIdx.x;
    int node = gtid >> 6;
    if (node >= N_NODES) return;
    int lane = threadIdx.x & 63;
    int g = lane >> 4, lr = lane & 15;                    // 4 groups x 16 lanes
    const u32* xrow = reinterpret_cast<const u32*>(xa);   // row stride 128 u32
    const u16* idx = ell + (size_t)node * ELLCAP;
    int deg = cnt[node];
    if (deg > ELLCAP) deg = ELLCAP;
    float a[8] = {};                                      // features 8*lr .. 8*lr+7
    int j = 0;
    for (; j + 16 <= deg; j += 16) {
        int s0 = idx[j + g], s1 = idx[j + 4 + g], s2 = idx[j + 8 + g], s3 = idx[j + 12 + g];
        uint4 v0 = *reinterpret_cast<const uint4*>(xrow + (size_t)s0 * 128 + lr * 4);
        uint4 v1 = *reinterpret_cast<const uint4*>(xrow + (size_t)s1 * 128 + lr * 4);
        uint4 v2 = *reinterpret_cast<const uint4*>(xrow + (size_t)s2 * 128 + lr * 4);
        uint4 v3 = *reinterpret_cast<const uint4*>(xrow + (size_t)s3 * 128 + lr * 4);
        ACC8(v0); ACC8(v1); ACC8(v2); ACC8(v3);
    }
    for (; j + 4 <= deg; j += 4) {
        int s0 = idx[j + g];
        uint4 v0 = *reinterpret_cast<const uint4*>(xrow + (size_t)s0 * 128 + lr * 4);
        ACC8(v0);
    }
    if (g < deg - j) {                                    // tail 0..3, predicated
        int s0 = idx[j + g];
        uint4 v0 = *reinterpret_cast<const uint4*>(xrow + (size_t)s0 * 128 + lr * 4);
        ACC8(v0);
    }
    #pragma unroll
    for (int k = 0; k < 8; ++k) {                         // reduce over 4 groups
        a[k] += __shfl_xor(a[k], 16);
        a[k] += __shfl_xor(a[k], 32);
    }
    if (g == 0) {
        float invd = 1.0f / fmaxf((float)deg, 1.0f);
        uint4 pk;
        pk.x = (u32)f2bf(a[0] * invd) | ((u32)f2bf(a[1] * invd) << 16);
        pk.y = (u32)f2bf(a[2] * invd) | ((u32)f2bf(a[3] * invd) << 16);
        pk.z = (u32)f2bf(a[4] * invd) | ((u32)f2bf(a[5] * invd) << 16);
        pk.w = (u32)f2bf(a[6] * invd) | ((u32)f2bf(a[7] * invd) << 16);
        *reinterpret_cast<uint4*>(reinterpret_cast<u32*>(xa) + (size_t)node * 128 + 64 + lr * 4) = pk;
    }
}

// ---------------- gather 2: out[n][:] += mean of t[s][:] (R3-proven) ----------------
__global__ __launch_bounds__(256) void gather2_kernel(const int* __restrict__ cnt,
                                                      const u16* __restrict__ ell,
                                                      const u16* __restrict__ t,
                                                      float* __restrict__ out) {
    int gtid = blockIdx.x * 256 + threadIdx.x;
    int node = gtid >> 6;
    if (node >= N_NODES) return;
    int lane = threadIdx.x & 63;
    int g = lane >> 3, lr = lane & 7;                     // 8 groups x 8 lanes
    const u32* trow = reinterpret_cast<const u32*>(t);    // row stride 32 u32
    const u16* idx = ell + (size_t)node * ELLCAP;
    int deg = cnt[node];
    if (deg > ELLCAP) deg = ELLCAP;
    float a[8] = {};                                      // features 8*lr .. 8*lr+7
    int j = 0;
    for (; j + 16 <= deg; j += 16) {
        int s0 = idx[j + g], s1 = idx[j + 8 + g];
        uint4 v0 = *reinterpret_cast<const uint4*>(trow + (size_t)s0 * 32 + lr * 4);
        uint4 v1 = *reinterpret_cast<const uint4*>(trow + (size_t)s1 * 32 + lr * 4);
        ACC8(v0); ACC8(v1);
    }
    for (; j + 8 <= deg; j += 8) {
        int s0 = idx[j + g];
        uint4 v0 = *reinterpret_cast<const uint4*>(trow + (size_t)s0 * 32 + lr * 4);
        ACC8(v0);
    }
    if (g < deg - j) {                                    // tail 0..7, predicated
        int s0 = idx[j + g];
        uint4 v0 = *reinterpret_cast<const uint4*>(trow + (size_t)s0 * 32 + lr * 4);
        ACC8(v0);
    }
    #pragma unroll
    for (int k = 0; k < 8; ++k) {                         // reduce over 8 groups
        a[k] += __shfl_xor(a[k], 8);
        a[k] += __shfl_xor(a[k], 16);
        a[k] += __shfl_xor(a[k], 32);
    }
    if (g == 0) {
        float invd = 1.0f / fmaxf((float)deg, 1.0f);
        float* o = out + (size_t)node * NCLASS + lr * 8;
        float4 o0 = *reinterpret_cast<float4*>(o);
        float4 o1 = *reinterpret_cast<float4*>(o + 4);
        o0.x += a[0] * invd; o0.y += a[1] * invd; o0.z += a[2] * invd; o0.w += a[3] * invd;
        o1.x += a[4] * invd; o1.y += a[5] * invd; o1.z += a[6] * invd; o1.w += a[7] * invd;
        *reinterpret_cast<float4*>(o) = o0;
        *reinterpret_cast<float4*>(o + 4) = o1;
    }
}

// ---------------- fused GEMM 1+2: h never leaves LDS ----------------
// Phase 1: h = relu(xa @ W1t^T + b1) per 128-row block, both 128-col halves
// sequentially (acc[4][4] reused -> no R13 VGPR regression), bf16 into hs[]
// with k-XOR swizzle (col ^ ((row&7)<<3)): fragments stay 8-contiguous, the
// 512B row stride spreads over 8 bank groups (~2-way, free per m136).
// Phase 2: A-fragments straight from hs, stage only W2t (8KB/step).
// Saves: h global round-trip (51MB), gemm2 prologue, one dispatch.
// LDS 80KB -> 2 blocks/CU.
__global__ __launch_bounds__(256) void gemm12_fused(const u16* __restrict__ xa,
                                                    const u16* __restrict__ W1t,
                                                    const float* __restrict__ b1,
                                                    const u16* __restrict__ W2t,
                                                    const float* __restrict__ b2,
                                                    u16* __restrict__ t,
                                                    float* __restrict__ out) {
    __shared__ u16 As[128 * 32];
    __shared__ u16 Bs[128 * 32];
    __shared__ u16 hs[128 * 256];   // 64KB swizzled h tile
    const int tid = threadIdx.x;
    const int r0 = blockIdx.x * 128;
    const int wid = tid >> 6, ln = tid & 63;
    const int wm = (wid & 1) * 64, wn = (wid >> 1) * 64;
    const int lr = ln & 15;
    const int lq = ln >> 4;

    // ---- phase 1: two column halves of h ----
    #pragma unroll 1
    for (int n0 = 0; n0 < 256; n0 += 128) {
        f32x4 acc[4][4] = {};
        for (int k0 = 0; k0 < 256; k0 += 32) {
            #pragma unroll
            for (int it = 0; it < 2; ++it) {
                int c   = it * 256 + tid;      // chunk 0..511
                int row = c >> 2;
                int ko  = (c & 3) * 8;
                GLOAD_LDS16(xa  + (size_t)(r0 + row) * 256 + k0 + ko, As + c * 8);
                GLOAD_LDS16(W1t + (size_t)(n0 + row) * 256 + k0 + ko, Bs + c * 8);
            }
            __syncthreads();

            s16x8 af[4], bf[4];
            #pragma unroll
            for (int i = 0; i < 4; ++i)
                af[i] = *reinterpret_cast<const s16x8*>(As + (wm + i * 16 + lr) * 32 + lq * 8);
            #pragma unroll
            for (int j = 0; j < 4; ++j)
                bf[j] = *reinterpret_cast<const s16x8*>(Bs + (wn + j * 16 + lr) * 32 + lq * 8);
            #pragma unroll
            for (int i = 0; i < 4; ++i)
                #pragma unroll
                for (int j = 0; j < 4; ++j)
                    acc[i][j] = __builtin_amdgcn_mfma_f32_16x16x32_bf16(af[i], bf[j], acc[i][j], 0, 0, 0);
            __syncthreads();
        }
        // epilogue -> hs (swizzled), relu+bias, bf16
        #pragma unroll
        for (int i = 0; i < 4; ++i) {
            #pragma unroll
            for (int j = 0; j < 4; ++j) {
                int col = n0 + wn + j * 16 + lr;
                float bias = b1[col];
                #pragma unroll
                for (int r = 0; r < 4; ++r) {
                    int row = wm + i * 16 + lq * 4 + r;   // local 0..127
                    hs[row * 256 + (col ^ ((row & 7) << 3))] =
                        f2bf(fmaxf(acc[i][j][r] + bias, 0.0f));
                }
            }
        }
    }

    // ---- phase 2: t/out = hs @ W2t^T (+b2) ----
    f32x4 acc[4][4] = {};
    for (int k0 = 0; k0 < 256; k0 += 32) {
        {
            int c0 = tid, c1 = 256 + tid;
            GLOAD_LDS16(W2t + (size_t)(c0 >> 2) * 256 + k0 + (c0 & 3) * 8, Bs + c0 * 8);
            GLOAD_LDS16(W2t + (size_t)(c1 >> 2) * 256 + k0 + (c1 & 3) * 8, Bs + c1 * 8);
        }
        __syncthreads();   // also orders phase-1 hs writes before first hs reads

        s16x8 af[4], bf[4];
        #pragma unroll
        for (int i = 0; i < 4; ++i) {
            int row = wm + i * 16 + lr;
            af[i] = *reinterpret_cast<const s16x8*>(hs + row * 256 + ((k0 + lq * 8) ^ ((row & 7) << 3)));
        }
        #pragma unroll
        for (int j = 0; j < 4; ++j)
            bf[j] = *reinterpret_cast<const s16x8*>(Bs + (wn + j * 16 + lr) * 32 + lq * 8);
        #pragma unroll
        for (int i = 0; i < 4; ++i)
            #pragma unroll
            for (int j = 0; j < 4; ++j)
                acc[i][j] = __builtin_amdgcn_mfma_f32_16x16x32_bf16(af[i], bf[j], acc[i][j], 0, 0, 0);
        __syncthreads();
    }

    #pragma unroll
    for (int i = 0; i < 4; ++i) {
        #pragma unroll
        for (int j = 0; j < 4; ++j) {
            int col = wn + j * 16 + lr;   // 0..127
            #pragma unroll
            for (int r = 0; r < 4; ++r) {
                int row = r0 + wm + i * 16 + lq * 4 + r;
                if (row >= N_NODES) continue;
                if (col < NCLASS) {
                    t[(size_t)row * NCLASS + col] = f2bf(acc[i][j][r]);
                } else {
                    int c = col - NCLASS;
                    out[(size_t)row * NCLASS + c] = acc[i][j][r] + b2[c];
                }
            }
        }
    }
}

extern "C" void kernel_launch(void* const* d_in, const int* in_sizes, int n_in,
                              void* d_out, int out_size, void* d_ws, size_t ws_size,
                              hipStream_t stream) {
    const float* x    = (const float*)d_in[0];
    const int*   ei   = (const int*)d_in[1];
    const float* W1n  = (const float*)d_in[2];
    const float* W1r  = (const float*)d_in[3];
    const float* b1   = (const float*)d_in[4];
    const float* W2n  = (const float*)d_in[5];
    const float* W2r  = (const float*)d_in[6];
    const float* b2   = (const float*)d_in[7];
    float* out = (float*)d_out;

    // workspace: gcnt u32[64] | bbuf u32[56<<14] | cnt int[50048] | ell u16[50000*64]
    //          | xa u16[50048*256] (padded: last gemm block stages rows 50000..50047)
    //          | t u16[50000*64] | W1t | W2t          (h eliminated by fusion)
    u32* gcnt = (u32*)d_ws;
    u32* bbuf = gcnt + 64;
    int* cnt  = (int*)(bbuf + ((size_t)NBUCK << 14));
    u16* ell  = (u16*)(cnt + 50048);
    u16* xa   = ell + (size_t)N_NODES * ELLCAP;
    u16* t    = xa + (size_t)50048 * 256;
    u16* W1t  = t  + (size_t)N_NODES * 64;
    u16* W2t  = W1t + 65536;

    hipMemsetAsync(gcnt, 0, 64 * sizeof(u32), stream);

    // bin edges + bf16 converts (one dispatch), then atomic-free ELL build
    prep_kernel<<<BIN_B + CVTX_B + CVTW_B, 256, 0, stream>>>(
        x, ei, W1r, W1n, W2n, W2r, xa, gcnt, bbuf, W1t, W2t);
    ell_build_kernel<<<NFINE, 512, 0, stream>>>(bbuf, gcnt, cnt, ell);

    // layer 1 aggregation
    gather1_kernel<<<(N_NODES * 64 + 255) / 256, 256, 0, stream>>>(cnt, ell, xa);

    // fused layer-1 + layer-2 GEMMs (h stays in LDS)
    gemm12_fused<<<NFINE, 256, 0, stream>>>(xa, W1t, b1, W2t, b2, t, out);

    // layer 2 aggregation
    gather2_kernel<<<(N_NODES * 64 + 255) / 256, 256, 0, stream>>>(cnt, ell, t, out);
}